// Round 7
// baseline (125.670 us; speedup 1.0000x reference)
//
#include <hip/hip_runtime.h>
#include <hip/hip_bf16.h>

#define NS_TOT 2000
#define NA 1000
#define NI 5
#define NH 32
#define NATB 8                     // atoms per block
#define NCHUNK 16                  // struct-chunks (2000/16 = 125 structs/chunk)
#define SCHUNK 125
#define W2LD 40                    // sW2T leading dim (80B rows, bank-spread)

typedef __attribute__((ext_vector_type(2)))  float f32x2;
typedef __attribute__((ext_vector_type(8)))  short short8;   // 8 bf16 = 4 VGPR
typedef __attribute__((ext_vector_type(16))) float f32x16;   // MFMA 32x32 acc

struct f4pair  { f32x2 a, b; };
struct accpair { f32x2 p[8]; };

// Packed Pade[5/4] tanh, paired reciprocal (R15, passing: absmax 0.015625).
__device__ __forceinline__ f32x2 tanh_pk(f32x2 X) {
    f32x2 z = X * X;
    f32x2 n = (z + 105.0f) * z + 945.0f;
    f32x2 d = (z * 15.0f + 420.0f) * z + 945.0f;
    const float rr = __builtin_amdgcn_rcpf(d.x * d.y);
    f32x2 r;
    r.x = rr * d.y;
    r.y = rr * d.x;
    f32x2 t = X * n * r;
    t.x = __builtin_amdgcn_fmed3f(t.x, -1.0f, 1.0f);
    t.y = __builtin_amdgcn_fmed3f(t.y, -1.0f, 1.0f);
    return t;
}

__device__ __forceinline__ unsigned short f2bf_rne(float x) {
    unsigned u = __float_as_uint(x);
    unsigned r = u + 0x7FFFu + ((u >> 16) & 1u);
    return (unsigned short)(r >> 16);
}
__device__ __forceinline__ unsigned pack2(float a, float b) {
    __hip_bfloat162 p = __float22bfloat162_rn(make_float2(a, b));
    unsigned u; __builtin_memcpy(&u, &p, 4); return u;
}
__device__ __forceinline__ unsigned tanh2_pack(float a, float b) {
    f32x2 X = {a, b};
    f32x2 t = tanh_pk(X);
    return pack2(t.x, t.y);
}

// R17 = R16 with the g-bug fixed: g is (S, A, I) -- PER-ATOM inputs. R16
// wrongly reused g[s][a0] for all 8 atoms (absmax 4.3). Fix: each lane
// loads g[s][a0..a0+7][:] = 160 CONTIGUOUS bytes (10 aligned float4s) and
// builds 8 per-atom B-fragments from registers (24 pack2, static indexing).
// The VMEM-coalescing premise survives: dense 160B/lane instead of 5
// scattered dwords (~4-8x fewer cache-line requests), stores coalesced 8x.
// Per-atom MFMA/permute/epilogue math = proven R12-R15 chain verbatim.
__global__ __attribute__((amdgpu_flat_work_group_size(256, 256),
                          amdgpu_waves_per_eu(3, 4)))
void mlp_mfma(
    const float* __restrict__ g,
    const float* __restrict__ W1, const float* __restrict__ b1,
    const float* __restrict__ W2, const float* __restrict__ b2,
    const float* __restrict__ W3, const float* __restrict__ b3,
    float* __restrict__ out)
{
    // XCD-chunked swizzle (bijective: 2000 % 8 == 0). A group's 16 chunk-
    // blocks get consecutive swz -> mostly same XCD -> weight L2 reuse.
    const int bid  = blockIdx.x;
    const int swz  = (bid & 7) * 250 + (bid >> 3);
    const int grp  = swz >> 4;          // [0,125)
    const int chunk= swz & 15;          // [0,16)
    const int a0   = grp * NATB;

    const int t = threadIdx.x;
    const int lane = t & 63, wid = t >> 6;
    const int l31 = lane & 31, half = lane >> 5;

    __shared__ __align__(16) unsigned short sW1T[NATB * 64 * 8];   // 8KB: rows 32..63 = 0
    __shared__ __align__(16) unsigned short sW2T[NATB * NH * W2LD];// 20KB: W2^T per atom
    __shared__ __align__(16) float sB2f[NATB * NH];                // 1KB
    __shared__ __align__(16) float sW3f[NATB * NH];                // 1KB

    // ---- stage weights for 8 atoms (all loads fully coalesced) ----
    for (int idx = t; idx < NATB * NH * NH; idx += 256) {
        const int jat = idx >> 10, e = idx & 1023, k = e >> 5, m = e & 31;
        sW2T[jat * (NH * W2LD) + m * W2LD + k] =
            f2bf_rne(W2[(size_t)(a0 + jat) * NH * NH + e]);
    }
    {   // t in [0,256): jat = t>>5, m = t&31  (one real row + one zero row each)
        const int jat = t >> 5, m = t & 31;
        const int rbase = jat * 512 + m * 8;
        #pragma unroll
        for (int i = 0; i < NI; ++i)
            sW1T[rbase + i] = f2bf_rne(W1[(size_t)(a0 + jat) * NI * NH + i * NH + m]);
        sW1T[rbase + 5] = f2bf_rne(b1[(a0 + jat) * NH + m]);
        sW1T[rbase + 6] = 0;
        sW1T[rbase + 7] = 0;
        // zero half (rows 32..63): A's K-pad rows
        *(uint4*)(sW1T + jat * 512 + 256 + m * 8) = make_uint4(0, 0, 0, 0);
        sB2f[t] = b2[(a0 + jat) * NH + m];
        sW3f[t] = W3[(a0 + jat) * NH + m];
    }
    __syncthreads();

    // ---- per-wave: 32 structs x 8 atoms ----
    const int sblk  = chunk * SCHUNK;
    const int slast = sblk + SCHUNK - 1;
    const int s     = sblk + wid * 32 + l31;
    const int sl    = (s < slast) ? s : slast;     // clamp (pad structs 125..127)

    // g[sl][a0..a0+7][0..4]: 160 contiguous bytes, 16B-aligned
    // ((sl*1000 + grp*8)*20 bytes: 20000 % 16 == 0, grp*160 % 16 == 0).
    // Both halves load the same struct (half1's B-words feed A's zero rows).
    const float* gp = g + ((size_t)sl * NA + a0) * NI;
    float gf[40];
    #pragma unroll
    for (int q = 0; q < 10; ++q) {
        const float4 v = ((const float4*)gp)[q];
        gf[4*q+0] = v.x; gf[4*q+1] = v.y; gf[4*q+2] = v.z; gf[4*q+3] = v.w;
    }
    // per-atom B-frag words (K slots: g0..g4, 1.0(bias), 0, 0) -- static idx
    unsigned gw[24];
    #pragma unroll
    for (int j = 0; j < NATB; ++j) {
        gw[3*j+0] = pack2(gf[5*j+0], gf[5*j+1]);
        gw[3*j+1] = pack2(gf[5*j+2], gf[5*j+3]);
        gw[3*j+2] = pack2(gf[5*j+4], 1.0f);
    }

    const float4 b3q0 = *(const float4*)(b3 + a0);      // grp*32B aligned
    const float4 b3q1 = *(const float4*)(b3 + a0 + 4);
    const float b3v[8] = {b3q0.x, b3q0.y, b3q0.z, b3q0.w,
                          b3q1.x, b3q1.y, b3q1.z, b3q1.w};

    const f32x16 zacc = {0,0,0,0,0,0,0,0,0,0,0,0,0,0,0,0};
    float eres[8];

    #pragma unroll
    for (int jat = 0; jat < NATB; ++jat) {
        // L1 A-fragment: rows 32..63 pre-zeroed in LDS
        const short8 afl1 = __builtin_bit_cast(short8,
            *(const uint4*)(sW1T + jat * 512 + lane * 8));
        // L1 B-fragment for THIS atom
        const uint4 bu0 = make_uint4(gw[3*jat], gw[3*jat+1], gw[3*jat+2], 0u);
        const short8 gb0 = __builtin_bit_cast(short8, bu0);
        const f32x16 d = __builtin_amdgcn_mfma_f32_32x32x16_bf16(afl1, gb0, zacc, 0, 0, 0);

        // ---- mid-layer tanh + C->B permute (verbatim R13-R15 math) ----
        // C row of reg r = (r&3) + 8*(r>>2) + 4*half; swap(a,b).x = {a_lo,b_lo},
        // .y = {a_hi,b_hi} -> B-frag words (k = half*8 + 2w, 2w+1).
        short8 bk0, bk1;
        {
            const unsigned p0 = tanh2_pack(d[0],  d[1]);
            const unsigned p1 = tanh2_pack(d[2],  d[3]);
            const unsigned p2 = tanh2_pack(d[4],  d[5]);
            const unsigned p3 = tanh2_pack(d[6],  d[7]);
            const unsigned p4 = tanh2_pack(d[8],  d[9]);
            const unsigned p5 = tanh2_pack(d[10], d[11]);
            const unsigned p6 = tanh2_pack(d[12], d[13]);
            const unsigned p7 = tanh2_pack(d[14], d[15]);
            auto s02 = __builtin_amdgcn_permlane32_swap(p0, p2, false, false);
            auto s13 = __builtin_amdgcn_permlane32_swap(p1, p3, false, false);
            auto s46 = __builtin_amdgcn_permlane32_swap(p4, p6, false, false);
            auto s57 = __builtin_amdgcn_permlane32_swap(p5, p7, false, false);
            const uint4 u0 = make_uint4(s02[0], s13[0], s02[1], s13[1]);
            const uint4 u1 = make_uint4(s46[0], s57[0], s46[1], s57[1]);
            bk0 = __builtin_bit_cast(short8, u0);
            bk1 = __builtin_bit_cast(short8, u1);
        }

        // ---- layer 2: b2 as C-input (broadcast quads, conflict-free) ----
        const float* b2p = sB2f + jat * NH;
        const float4 q0 = ((const float4*)b2p)[0 + half];
        const float4 q1 = ((const float4*)b2p)[2 + half];
        const float4 q2 = ((const float4*)b2p)[4 + half];
        const float4 q3 = ((const float4*)b2p)[6 + half];
        const f32x16 b2a = {q0.x, q0.y, q0.z, q0.w, q1.x, q1.y, q1.z, q1.w,
                            q2.x, q2.y, q2.z, q2.w, q3.x, q3.y, q3.z, q3.w};
        const unsigned short* w2p = sW2T + jat * (NH * W2LD) + l31 * W2LD + half * 8;
        const short8 af0 = __builtin_bit_cast(short8, *(const uint4*)w2p);
        const short8 af1 = __builtin_bit_cast(short8, *(const uint4*)(w2p + 16));
        f32x16 acc = __builtin_amdgcn_mfma_f32_32x32x16_bf16(af0, bk0, b2a, 0, 0, 0);
        acc = __builtin_amdgcn_mfma_f32_32x32x16_bf16(af1, bk1, acc, 0, 0, 0);

        // ---- epilogue (verbatim): packed tanh + packed layer-3 dot ----
        const float* w3b = sW3f + jat * NH;
        const f4pair w3p0 = __builtin_bit_cast(f4pair, ((const float4*)w3b)[0 + half]);
        const f4pair w3p1 = __builtin_bit_cast(f4pair, ((const float4*)w3b)[2 + half]);
        const f4pair w3p2 = __builtin_bit_cast(f4pair, ((const float4*)w3b)[4 + half]);
        const f4pair w3p3 = __builtin_bit_cast(f4pair, ((const float4*)w3b)[6 + half]);
        const accpair ap = __builtin_bit_cast(accpair, acc);
        f32x2 p = {0.f, 0.f};
        p += tanh_pk(ap.p[0]) * w3p0.a;  p += tanh_pk(ap.p[1]) * w3p0.b;
        p += tanh_pk(ap.p[2]) * w3p1.a;  p += tanh_pk(ap.p[3]) * w3p1.b;
        p += tanh_pk(ap.p[4]) * w3p2.a;  p += tanh_pk(ap.p[5]) * w3p2.b;
        p += tanh_pk(ap.p[6]) * w3p3.a;  p += tanh_pk(ap.p[7]) * w3p3.b;
        const float e = p.x + p.y;
        // cross-half reduce: lane's 16 rows + partner's 16 rows = full 32-dot
        auto es = __builtin_amdgcn_permlane32_swap(__float_as_uint(e),
                                                   __float_as_uint(e),
                                                   false, false);
        eres[jat] = __uint_as_float(es[0]) + __uint_as_float(es[1]) + b3v[jat];
    }

    // ---- coalesced store: 8 consecutive atoms = 32B contiguous per struct ----
    if (half == 0 && s <= slast) {
        const float4 o0 = {eres[0], eres[1], eres[2], eres[3]};
        const float4 o1 = {eres[4], eres[5], eres[6], eres[7]};
        float* op = out + (size_t)s * NA + a0;          // 16B-aligned
        *(float4*)op       = o0;
        *(float4*)(op + 4) = o1;
    }
}

extern "C" void kernel_launch(void* const* d_in, const int* in_sizes, int n_in,
                              void* d_out, int out_size, void* d_ws, size_t ws_size,
                              hipStream_t stream) {
    const float* g  = (const float*)d_in[0];
    const float* W1 = (const float*)d_in[1];
    const float* b1 = (const float*)d_in[2];
    const float* W2 = (const float*)d_in[3];
    const float* b2 = (const float*)d_in[4];
    const float* W3 = (const float*)d_in[5];
    const float* b3 = (const float*)d_in[6];
    float* out = (float*)d_out;
    mlp_mfma<<<dim3(125 * NCHUNK), dim3(256), 0, stream>>>(g, W1, b1, W2, b2, W3, b3, out);
}

// Round 8
// 120.728 us; speedup vs baseline: 1.0409x; 1.0409x over previous
//
#include <hip/hip_runtime.h>
#include <hip/hip_bf16.h>

#define NS_TOT 2000
#define NA 1000
#define NI 5
#define NH 32
#define SHALF 1000                 // structs per block (two blocks per atom)
#define W2LD 40                    // sW2T leading dim (80B rows, bank-spread)

typedef __attribute__((ext_vector_type(2)))  float f32x2;
typedef __attribute__((ext_vector_type(8)))  short short8;   // 8 bf16 = 4 VGPR
typedef __attribute__((ext_vector_type(16))) float f32x16;   // MFMA 32x32 acc

struct f4pair  { f32x2 a, b; };
struct accpair { f32x2 p[8]; };

// Packed Pade[5/4] tanh, paired reciprocal (R15/R17, passing: absmax 0.015625).
__device__ __forceinline__ f32x2 tanh_pk(f32x2 X) {
    f32x2 z = X * X;
    f32x2 n = (z + 105.0f) * z + 945.0f;
    f32x2 d = (z * 15.0f + 420.0f) * z + 945.0f;
    const float rr = __builtin_amdgcn_rcpf(d.x * d.y);
    f32x2 r;
    r.x = rr * d.y;
    r.y = rr * d.x;
    f32x2 t = X * n * r;
    t.x = __builtin_amdgcn_fmed3f(t.x, -1.0f, 1.0f);
    t.y = __builtin_amdgcn_fmed3f(t.y, -1.0f, 1.0f);
    return t;
}

__device__ __forceinline__ unsigned short f2bf_rne(float x) {
    unsigned u = __float_as_uint(x);
    unsigned r = u + 0x7FFFu + ((u >> 16) & 1u);
    return (unsigned short)(r >> 16);
}
__device__ __forceinline__ unsigned pack2(float a, float b) {
    __hip_bfloat162 p = __float22bfloat162_rn(make_float2(a, b));
    unsigned u; __builtin_memcpy(&u, &p, 4); return u;
}
__device__ __forceinline__ unsigned tanh2_pack(float a, float b) {
    f32x2 X = {a, b};
    f32x2 t = tanh_pk(X);
    return pack2(t.x, t.y);
}

// R18: back to the best structure (R13: 1 atom/block, hoisted b2acc/w3 --
// R17 proved the 8-atom variant re-adds per-iter costs and VMEM scatter was
// never the bound), WIDENED to 4 independent struct-tiles per iteration
// (128 structs/wave-iter, 2 iters). Rationale: VALUBusy pinned at ~62-67%
// with ~2.5 effective waves/SIMD in every structure tried -> per-wave
// dependency latency is the residual; 4 independent L1->tanh->permute->L2->
// epilogue chains give the scheduler ILP at every stall point. Bit-identical
// per-struct math. waves_per_eu(2,4): live set ~140-150 VGPR (4 d-tiles +
// 4 acc-tiles), 256-reg budget, no spill (R11 lesson).
__global__ __attribute__((amdgpu_flat_work_group_size(256, 256),
                          amdgpu_waves_per_eu(2, 4)))
void mlp_mfma(
    const float* __restrict__ g,
    const float* __restrict__ W1, const float* __restrict__ b1,
    const float* __restrict__ W2, const float* __restrict__ b2,
    const float* __restrict__ W3, const float* __restrict__ b3,
    float* __restrict__ out)
{
    const int bid   = blockIdx.x;
    const int araw  = bid % NA;
    const int chunk = bid / NA;
    const int a = (araw >> 3) + 125 * (araw & 7);   // same-XCD atom swizzle
    const int t = threadIdx.x;
    const int lane = t & 63, wid = t >> 6;
    const int l31 = lane & 31, half = lane >> 5;

    const int sbase_blk = chunk * SHALF;
    const int send      = sbase_blk + SHALF;

    __shared__ __align__(16) unsigned short sW2T[NH * W2LD];  // W2^T bf16 [m][k]
    __shared__ __align__(16) unsigned short sW1T[NH * 8];     // [m]{W1[0..4][m],b1[m],0,0}
    __shared__ __align__(16) float sB2[NH];
    __shared__ __align__(16) float sW3[NH];

    for (int idx = t; idx < NH * NH; idx += 256) {
        const int i = idx >> 5, j = idx & 31;       // i = k row of W2, j = m col
        sW2T[j * W2LD + i] = f2bf_rne(W2[(size_t)a * NH * NH + idx]);
    }
    if (t < NH) {
        sB2[t] = b2[a * NH + t];
        sW3[t] = W3[a * NH + t];
        const int m = t;
        #pragma unroll
        for (int i = 0; i < NI; ++i)
            sW1T[m * 8 + i] = f2bf_rne(W1[(size_t)a * NI * NH + i * NH + m]);
        sW1T[m * 8 + 5] = f2bf_rne(b1[a * NH + m]);
        sW1T[m * 8 + 6] = 0;
        sW1T[m * 8 + 7] = 0;
    }
    __syncthreads();

    // persistent fragments (hoisted once per block -- the R12 win R17 lost)
    const short8 zero8 = {0,0,0,0,0,0,0,0};
    const short8 w1ld = __builtin_bit_cast(short8, *(const uint4*)(sW1T + l31 * 8));
    const short8 afl1 = half ? zero8 : w1ld;   // A[m][k]: half1 = K-pad zeros
    const short8 af0 = __builtin_bit_cast(short8, *(const uint4*)(sW2T + l31 * W2LD + half * 8));
    const short8 af1 = __builtin_bit_cast(short8, *(const uint4*)(sW2T + l31 * W2LD + 16 + half * 8));
    const float4 b2q0 = ((const float4*)sB2)[0 + half];
    const float4 b2q1 = ((const float4*)sB2)[2 + half];
    const float4 b2q2 = ((const float4*)sB2)[4 + half];
    const float4 b2q3 = ((const float4*)sB2)[6 + half];
    const f4pair w3p0 = __builtin_bit_cast(f4pair, ((const float4*)sW3)[0 + half]);
    const f4pair w3p1 = __builtin_bit_cast(f4pair, ((const float4*)sW3)[2 + half]);
    const f4pair w3p2 = __builtin_bit_cast(f4pair, ((const float4*)sW3)[4 + half]);
    const f4pair w3p3 = __builtin_bit_cast(f4pair, ((const float4*)sW3)[6 + half]);
    const float bias3 = b3[a];
    const f32x16 zacc = {0,0,0,0,0,0,0,0,0,0,0,0,0,0,0,0};
    const f32x16 b2acc = {b2q0.x, b2q0.y, b2q0.z, b2q0.w,
                          b2q1.x, b2q1.y, b2q1.z, b2q1.w,
                          b2q2.x, b2q2.y, b2q2.z, b2q2.w,
                          b2q3.x, b2q3.y, b2q3.z, b2q3.w};

    // g loads for both rows of it=0 (xA = struct base+lane, xB = +64)
    float xA0, xA1, xA2, xA3, xA4, xB0, xB1, xB2, xB3, xB4;
    {
        const int sA = sbase_blk + wid * 128 + lane;
        const float* gp = g + ((size_t)sA * NA + a) * NI;
        xA0 = gp[0]; xA1 = gp[1]; xA2 = gp[2]; xA3 = gp[3]; xA4 = gp[4];
        const float* gq = g + ((size_t)(sA + 64) * NA + a) * NI;
        xB0 = gq[0]; xB1 = gq[1]; xB2 = gq[2]; xB3 = gq[3]; xB4 = gq[4];
    }

    #pragma unroll
    for (int it = 0; it < 2; ++it) {
        const int sA = sbase_blk + it * 512 + wid * 128 + lane;
        const int sB = sA + 64;

        // ---- prefetch it=1's rows under it=0's compute ----
        float yA0, yA1, yA2, yA3, yA4, yB0, yB1, yB2, yB3, yB4;
        if (it == 0) {
            const int pA = sA + 512;
            const int pAl = (pA < send) ? pA : (send - 1);
            const float* gp = g + ((size_t)pAl * NA + a) * NI;
            yA0 = gp[0]; yA1 = gp[1]; yA2 = gp[2]; yA3 = gp[3]; yA4 = gp[4];
            const int pB = pA + 64;
            const int pBl = (pB < send) ? pB : (send - 1);
            const float* gq = g + ((size_t)pBl * NA + a) * NI;
            yB0 = gq[0]; yB1 = gq[1]; yB2 = gq[2]; yB3 = gq[3]; yB4 = gq[4];
        }

        // ---- build 4 g B-fragments (tiles 0,1 from row A; 2,3 from row B) ----
        const unsigned gA01 = pack2(xA0, xA1);
        const unsigned gA23 = pack2(xA2, xA3);
        const unsigned gA45 = pack2(xA4, 1.0f);
        const unsigned gB01 = pack2(xB0, xB1);
        const unsigned gB23 = pack2(xB2, xB3);
        const unsigned gB45 = pack2(xB4, 1.0f);
        auto hA01 = __builtin_amdgcn_permlane32_swap(gA01, gA01, false, false);
        auto hA23 = __builtin_amdgcn_permlane32_swap(gA23, gA23, false, false);
        auto hA45 = __builtin_amdgcn_permlane32_swap(gA45, gA45, false, false);
        auto hB01 = __builtin_amdgcn_permlane32_swap(gB01, gB01, false, false);
        auto hB23 = __builtin_amdgcn_permlane32_swap(gB23, gB23, false, false);
        auto hB45 = __builtin_amdgcn_permlane32_swap(gB45, gB45, false, false);
        const short8 gb0 = __builtin_bit_cast(short8, make_uint4(gA01, gA23, gA45, 0u));
        const short8 gb1 = __builtin_bit_cast(short8, make_uint4(hA01[1], hA23[1], hA45[1], 0u));
        const short8 gb2 = __builtin_bit_cast(short8, make_uint4(gB01, gB23, gB45, 0u));
        const short8 gb3 = __builtin_bit_cast(short8, make_uint4(hB01[1], hB23[1], hB45[1], 0u));

        // ---- layer 1: 4 independent MFMAs ----
        f32x16 d0 = __builtin_amdgcn_mfma_f32_32x32x16_bf16(afl1, gb0, zacc, 0, 0, 0);
        f32x16 d1 = __builtin_amdgcn_mfma_f32_32x32x16_bf16(afl1, gb1, zacc, 0, 0, 0);
        f32x16 d2 = __builtin_amdgcn_mfma_f32_32x32x16_bf16(afl1, gb2, zacc, 0, 0, 0);
        f32x16 d3 = __builtin_amdgcn_mfma_f32_32x32x16_bf16(afl1, gb3, zacc, 0, 0, 0);

        // ---- mid-layer tanh + C->B permute, 4 independent streams ----
        // C row of reg r = (r&3) + 8*(r>>2) + 4*half; swap(a,b).x = {a_lo,b_lo},
        // .y = {a_hi,b_hi} -> B-frag words (k = half*8 + 2w, 2w+1).
        short8 bk0_0, bk1_0, bk0_1, bk1_1, bk0_2, bk1_2, bk0_3, bk1_3;
        #define TILE_CONV(DD, BK0, BK1) { \
            const unsigned p0 = tanh2_pack(DD[0],  DD[1]); \
            const unsigned p1 = tanh2_pack(DD[2],  DD[3]); \
            const unsigned p2 = tanh2_pack(DD[4],  DD[5]); \
            const unsigned p3 = tanh2_pack(DD[6],  DD[7]); \
            const unsigned p4 = tanh2_pack(DD[8],  DD[9]); \
            const unsigned p5 = tanh2_pack(DD[10], DD[11]); \
            const unsigned p6 = tanh2_pack(DD[12], DD[13]); \
            const unsigned p7 = tanh2_pack(DD[14], DD[15]); \
            auto s02 = __builtin_amdgcn_permlane32_swap(p0, p2, false, false); \
            auto s13 = __builtin_amdgcn_permlane32_swap(p1, p3, false, false); \
            auto s46 = __builtin_amdgcn_permlane32_swap(p4, p6, false, false); \
            auto s57 = __builtin_amdgcn_permlane32_swap(p5, p7, false, false); \
            BK0 = __builtin_bit_cast(short8, make_uint4(s02[0], s13[0], s02[1], s13[1])); \
            BK1 = __builtin_bit_cast(short8, make_uint4(s46[0], s57[0], s46[1], s57[1])); }
        TILE_CONV(d0, bk0_0, bk1_0)
        TILE_CONV(d1, bk0_1, bk1_1)
        TILE_CONV(d2, bk0_2, bk1_2)
        TILE_CONV(d3, bk0_3, bk1_3)
        #undef TILE_CONV

        // ---- layer 2: 8 MFMAs, 4 independent accumulators ----
        f32x16 acc0 = __builtin_amdgcn_mfma_f32_32x32x16_bf16(af0, bk0_0, b2acc, 0, 0, 0);
        acc0 = __builtin_amdgcn_mfma_f32_32x32x16_bf16(af1, bk1_0, acc0, 0, 0, 0);
        f32x16 acc1 = __builtin_amdgcn_mfma_f32_32x32x16_bf16(af0, bk0_1, b2acc, 0, 0, 0);
        acc1 = __builtin_amdgcn_mfma_f32_32x32x16_bf16(af1, bk1_1, acc1, 0, 0, 0);
        f32x16 acc2 = __builtin_amdgcn_mfma_f32_32x32x16_bf16(af0, bk0_2, b2acc, 0, 0, 0);
        acc2 = __builtin_amdgcn_mfma_f32_32x32x16_bf16(af1, bk1_2, acc2, 0, 0, 0);
        f32x16 acc3 = __builtin_amdgcn_mfma_f32_32x32x16_bf16(af0, bk0_3, b2acc, 0, 0, 0);
        acc3 = __builtin_amdgcn_mfma_f32_32x32x16_bf16(af1, bk1_3, acc3, 0, 0, 0);

        // ---- epilogue: 4 independent tanh+dot streams ----
        #define EPI(ACC, EOUT) { \
            const accpair ap = __builtin_bit_cast(accpair, ACC); \
            f32x2 p = {0.f, 0.f}; \
            p += tanh_pk(ap.p[0]) * w3p0.a;  p += tanh_pk(ap.p[1]) * w3p0.b; \
            p += tanh_pk(ap.p[2]) * w3p1.a;  p += tanh_pk(ap.p[3]) * w3p1.b; \
            p += tanh_pk(ap.p[4]) * w3p2.a;  p += tanh_pk(ap.p[5]) * w3p2.b; \
            p += tanh_pk(ap.p[6]) * w3p3.a;  p += tanh_pk(ap.p[7]) * w3p3.b; \
            EOUT = p.x + p.y; }
        float e0, e1, e2, e3;
        EPI(acc0, e0) EPI(acc1, e1) EPI(acc2, e2) EPI(acc3, e3)
        #undef EPI
        // cross-half reduce + full-wave stores (verbatim pattern, twice)
        auto es01 = __builtin_amdgcn_permlane32_swap(__float_as_uint(e0),
                                                     __float_as_uint(e1),
                                                     false, false);
        const float et01 = __uint_as_float(es01[0]) + __uint_as_float(es01[1]);
        if (sA < send) out[(size_t)sA * NA + a] = et01 + bias3;
        auto es23 = __builtin_amdgcn_permlane32_swap(__float_as_uint(e2),
                                                     __float_as_uint(e3),
                                                     false, false);
        const float et23 = __uint_as_float(es23[0]) + __uint_as_float(es23[1]);
        if (sB < send) out[(size_t)sB * NA + a] = et23 + bias3;

        if (it == 0) {
            xA0 = yA0; xA1 = yA1; xA2 = yA2; xA3 = yA3; xA4 = yA4;
            xB0 = yB0; xB1 = yB1; xB2 = yB2; xB3 = yB3; xB4 = yB4;
        }
    }
}

extern "C" void kernel_launch(void* const* d_in, const int* in_sizes, int n_in,
                              void* d_out, int out_size, void* d_ws, size_t ws_size,
                              hipStream_t stream) {
    const float* g  = (const float*)d_in[0];
    const float* W1 = (const float*)d_in[1];
    const float* b1 = (const float*)d_in[2];
    const float* W2 = (const float*)d_in[3];
    const float* b2 = (const float*)d_in[4];
    const float* W3 = (const float*)d_in[5];
    const float* b3 = (const float*)d_in[6];
    float* out = (float*)d_out;
    mlp_mfma<<<dim3(NA * 2), dim3(256), 0, stream>>>(g, W1, b1, W2, b2, W3, b3, out);
}